// Round 2
// baseline (1033.075 us; speedup 1.0000x reference)
//
#include <hip/hip_runtime.h>
#include <math.h>

#define B_ 4
#define S_ 4096
#define D_ 1024
#define T_ 128
#define NC_ 32
#define DECAY_ 0.95f

typedef __bf16 bf16;
typedef __bf16 bf16x8 __attribute__((ext_vector_type(8)));
typedef __bf16 bf16x4 __attribute__((ext_vector_type(4)));
typedef float f32x4 __attribute__((ext_vector_type(4)));

__device__ __forceinline__ f32x4 mfma16(bf16x8 a, bf16x8 b, f32x4 c) {
  return __builtin_amdgcn_mfma_f32_16x16x32_bf16(a, b, c, 0, 0, 0);
}

// ---------------- fp32 -> bf16 cast ----------------
__global__ void cast_kernel(const float* __restrict__ src, bf16* __restrict__ dst, int n) {
  int i = (blockIdx.x * blockDim.x + threadIdx.x) * 4;
  int stride = gridDim.x * blockDim.x * 4;
  for (; i < n; i += stride) {
    float4 f = *(const float4*)(src + i);
    bf16x4 o = { (bf16)f.x, (bf16)f.y, (bf16)f.z, (bf16)f.w };
    *(bf16x4*)(dst + i) = o;
  }
}

// ---------------- fused projection GEMM ----------------
// A[16384][1024] bf16, W[4096][1024] bf16 (rows = output features, K-major: y = x @ W.T)
// n in [0,1024): q (natural), [1024,2048): k -> kT[b][c][e][t], [2048,3072): v -> vT,
// [3072,4096): gate = sigmoid(x + bg) (natural)
__global__ __launch_bounds__(256) void gemm_proj(
    const bf16* __restrict__ A, const bf16* __restrict__ W,
    const float* __restrict__ bg,
    bf16* __restrict__ qo, bf16* __restrict__ kT,
    bf16* __restrict__ vT, bf16* __restrict__ go)
{
  __shared__ bf16 As[128 * 32];
  __shared__ bf16 Bs[128 * 32];
  const int K = 1024;
  int m0 = blockIdx.y * 128;
  int n0 = blockIdx.x * 128;
  int tid = threadIdx.x;
  int l = tid & 63, w = tid >> 6;
  int wr = w >> 1, wc = w & 1;

  const bf16* Ab = A + (long)m0 * K;
  const bf16* Wb = W + (long)n0 * K;
  int lrow = tid >> 2, lcol = (tid & 3) * 8;

  f32x4 acc[4][4] = {};

  bf16x8 a0 = *(const bf16x8*)(Ab + (long)lrow * K + lcol);
  bf16x8 a1 = *(const bf16x8*)(Ab + (long)(lrow + 64) * K + lcol);
  bf16x8 b0 = *(const bf16x8*)(Wb + (long)lrow * K + lcol);
  bf16x8 b1 = *(const bf16x8*)(Wb + (long)(lrow + 64) * K + lcol);

  for (int k0 = 0; k0 < K; k0 += 32) {
    __syncthreads();
    *(bf16x8*)(As + tid * 8) = a0;
    *(bf16x8*)(As + (tid + 256) * 8) = a1;
    *(bf16x8*)(Bs + tid * 8) = b0;
    *(bf16x8*)(Bs + (tid + 256) * 8) = b1;
    __syncthreads();
    if (k0 + 32 < K) {
      a0 = *(const bf16x8*)(Ab + (long)lrow * K + k0 + 32 + lcol);
      a1 = *(const bf16x8*)(Ab + (long)(lrow + 64) * K + k0 + 32 + lcol);
      b0 = *(const bf16x8*)(Wb + (long)lrow * K + k0 + 32 + lcol);
      b1 = *(const bf16x8*)(Wb + (long)(lrow + 64) * K + k0 + 32 + lcol);
    }
    bf16x8 af[4], bfr[4];
#pragma unroll
    for (int m = 0; m < 4; ++m)
      af[m] = *(const bf16x8*)(As + (wr * 64 + m * 16 + (l & 15)) * 32 + (l >> 4) * 8);
#pragma unroll
    for (int n = 0; n < 4; ++n)
      bfr[n] = *(const bf16x8*)(Bs + (wc * 64 + n * 16 + (l & 15)) * 32 + (l >> 4) * 8);
#pragma unroll
    for (int m = 0; m < 4; ++m)
#pragma unroll
      for (int n = 0; n < 4; ++n)
        acc[m][n] = mfma16(af[m], bfr[n], acc[m][n]);
  }

  int widx = n0 >> 10;          // which weight: 0=q 1=k 2=v 3=g
  int b = m0 >> 12;             // batch (4096 rows per batch; 128 | 4096)
  int srow0 = m0 & 4095;
  int chunk = srow0 >> 7;       // 128-row tile == one chunk

#pragma unroll
  for (int m = 0; m < 4; ++m) {
    int row = wr * 64 + m * 16 + (l >> 4) * 4;   // row-in-tile, +r
#pragma unroll
    for (int n = 0; n < 4; ++n) {
      int col = (n0 & 1023) + wc * 64 + n * 16 + (l & 15);  // feature e
      if (widx == 1 || widx == 2) {
        bf16* dst = (widx == 1) ? kT : vT;
        bf16x4 pk = { (bf16)acc[m][n][0], (bf16)acc[m][n][1],
                      (bf16)acc[m][n][2], (bf16)acc[m][n][3] };
        *(bf16x4*)(dst + ((long)(b * NC_ + chunk) * D_ + col) * T_ + row) = pk;
      } else if (widx == 0) {
#pragma unroll
        for (int r = 0; r < 4; ++r)
          qo[(long)(m0 + row + r) * D_ + col] = (bf16)acc[m][n][r];
      } else {
        float bgv = bg[col];
#pragma unroll
        for (int r = 0; r < 4; ++r) {
          float x = acc[m][n][r] + bgv;
          go[(long)(m0 + row + r) * D_ + col] = (bf16)(1.0f / (1.0f + __expf(-x)));
        }
      }
    }
  }
}

// ---------------- resident-state column-sliced scan ----------------
// block = (batch, 16-column slice). state[16][1024] fp32 lives in LDS across all chunks.
__global__ __launch_bounds__(256) void scan_kernel(
    const bf16* __restrict__ q, const bf16* __restrict__ kT,
    const bf16* __restrict__ vT, const bf16* __restrict__ g,
    bf16* __restrict__ mid)
{
  __shared__ float stf[16][D_ + 4];   // fp32 state, [e][d], padded (bank-conflict-free)
  __shared__ bf16 stb[16][D_ + 8];    // bf16 shadow for MFMA B-operand

  int blk = blockIdx.x;
  int b = blk >> 6;
  int e0 = (blk & 63) * 16;
  int tid = threadIdx.x, l = tid & 63, w = tid >> 6;

  for (int i = tid; i < 16 * (D_ + 4); i += 256) (&stf[0][0])[i] = 0.0f;
  __syncthreads();

  const float upd = (1.0f - DECAY_) / (float)T_;

  for (int n = 0; n < NC_; ++n) {
    const bf16* kTn = kT + (long)(b * NC_ + n) * D_ * T_;
    const bf16* vTn = vT + (long)(b * NC_ + n) * D_ * T_;

    // preload v B-fragments for the whole chunk (shared across all d-blocks)
    bf16x8 vb[4];
#pragma unroll
    for (int kk = 0; kk < 4; ++kk)
      vb[kk] = *(const bf16x8*)(vTn + (long)(e0 + (l & 15)) * T_ + kk * 32 + (l >> 4) * 8);

    // kv slice + state update: output [1024 d][16 e], K = t = 128
#pragma unroll 2
    for (int db = w; db < 64; db += 4) {
      int d0 = db * 16;
      f32x4 acc = {};
#pragma unroll
      for (int kk = 0; kk < 4; ++kk) {
        bf16x8 ka = *(const bf16x8*)(kTn + (long)(d0 + (l & 15)) * T_ + kk * 32 + (l >> 4) * 8);
        acc = mfma16(ka, vb[kk], acc);
      }
      int e = l & 15;
#pragma unroll
      for (int r = 0; r < 4; ++r) {
        int d = d0 + (l >> 4) * 4 + r;
        float s = stf[e][d] * DECAY_ + acc[r] * upd;
        stf[e][d] = s;
        stb[e][d] = (bf16)s;
      }
    }
    __syncthreads();

    // ret slice: [128 t][16 e], K = d = 1024. A = q (natural), B = stb.
    const bf16* qn = q + (long)(b * S_ + n * T_) * D_;
    f32x4 racc[2] = {};
#pragma unroll 4
    for (int kk = 0; kk < 32; ++kk) {
      bf16x8 sb = *(const bf16x8*)(&stb[l & 15][kk * 32 + (l >> 4) * 8]);
#pragma unroll
      for (int i = 0; i < 2; ++i) {
        int t0 = (w + i * 4) * 16;
        bf16x8 qa = *(const bf16x8*)(qn + (long)(t0 + (l & 15)) * D_ + kk * 32 + (l >> 4) * 8);
        racc[i] = mfma16(qa, sb, racc[i]);
      }
    }
    __syncthreads();

    // epilogue: ret * gate -> mid
#pragma unroll
    for (int i = 0; i < 2; ++i) {
      int t0 = (w + i * 4) * 16;
#pragma unroll
      for (int r = 0; r < 4; ++r) {
        int t = t0 + (l >> 4) * 4 + r;
        long idx = (long)(b * S_ + n * T_ + t) * D_ + e0 + (l & 15);
        float gv = (float)g[idx];
        mid[idx] = (bf16)(racc[i][r] * gv);
      }
    }
  }
}

// ---------------- output GEMM (fp32 out) ----------------
__global__ __launch_bounds__(256) void gemm_out(
    const bf16* __restrict__ A, const bf16* __restrict__ W,
    float* __restrict__ C)
{
  __shared__ bf16 As[128 * 32];
  __shared__ bf16 Bs[128 * 32];
  const int K = 1024;
  int m0 = blockIdx.y * 128;
  int n0 = blockIdx.x * 128;
  int tid = threadIdx.x;
  int l = tid & 63, w = tid >> 6;
  int wr = w >> 1, wc = w & 1;

  const bf16* Ab = A + (long)m0 * K;
  const bf16* Wb = W + (long)n0 * K;
  int lrow = tid >> 2, lcol = (tid & 3) * 8;

  f32x4 acc[4][4] = {};

  bf16x8 a0 = *(const bf16x8*)(Ab + (long)lrow * K + lcol);
  bf16x8 a1 = *(const bf16x8*)(Ab + (long)(lrow + 64) * K + lcol);
  bf16x8 b0 = *(const bf16x8*)(Wb + (long)lrow * K + lcol);
  bf16x8 b1 = *(const bf16x8*)(Wb + (long)(lrow + 64) * K + lcol);

  for (int k0 = 0; k0 < K; k0 += 32) {
    __syncthreads();
    *(bf16x8*)(As + tid * 8) = a0;
    *(bf16x8*)(As + (tid + 256) * 8) = a1;
    *(bf16x8*)(Bs + tid * 8) = b0;
    *(bf16x8*)(Bs + (tid + 256) * 8) = b1;
    __syncthreads();
    if (k0 + 32 < K) {
      a0 = *(const bf16x8*)(Ab + (long)lrow * K + k0 + 32 + lcol);
      a1 = *(const bf16x8*)(Ab + (long)(lrow + 64) * K + k0 + 32 + lcol);
      b0 = *(const bf16x8*)(Wb + (long)lrow * K + k0 + 32 + lcol);
      b1 = *(const bf16x8*)(Wb + (long)(lrow + 64) * K + k0 + 32 + lcol);
    }
    bf16x8 af[4], bfr[4];
#pragma unroll
    for (int m = 0; m < 4; ++m)
      af[m] = *(const bf16x8*)(As + (wr * 64 + m * 16 + (l & 15)) * 32 + (l >> 4) * 8);
#pragma unroll
    for (int n = 0; n < 4; ++n)
      bfr[n] = *(const bf16x8*)(Bs + (wc * 64 + n * 16 + (l & 15)) * 32 + (l >> 4) * 8);
#pragma unroll
    for (int m = 0; m < 4; ++m)
#pragma unroll
      for (int n = 0; n < 4; ++n)
        acc[m][n] = mfma16(af[m], bfr[n], acc[m][n]);
  }

#pragma unroll
  for (int m = 0; m < 4; ++m) {
    int row = m0 + wr * 64 + m * 16 + (l >> 4) * 4;
#pragma unroll
    for (int n = 0; n < 4; ++n) {
      int col = n0 + wc * 64 + n * 16 + (l & 15);
#pragma unroll
      for (int r = 0; r < 4; ++r)
        C[(long)(row + r) * D_ + col] = acc[m][n][r];
    }
  }
}

// ---------------- launcher ----------------
extern "C" void kernel_launch(void* const* d_in, const int* in_sizes, int n_in,
                              void* d_out, int out_size, void* d_ws, size_t ws_size,
                              hipStream_t stream) {
  const float* h  = (const float*)d_in[0];
  // d_in[1] = chunk_size (always 128 here)
  const float* Wq = (const float*)d_in[2];
  const float* Wk = (const float*)d_in[3];
  const float* Wv = (const float*)d_in[4];
  const float* Wo = (const float*)d_in[5];
  const float* Wg = (const float*)d_in[6];
  const float* bg = (const float*)d_in[7];
  float* out = (float*)d_out;

  bf16* ws = (bf16*)d_ws;
  const long NHD = (long)B_ * S_ * D_;   // 16,777,216
  const long NW  = (long)D_ * D_;        // 1,048,576

  bf16* h_bf  = ws;  ws += NHD;
  bf16* Wcat  = ws;  ws += 4 * NW;
  bf16* Wo_bf = ws;  ws += NW;
  bf16* q_bf  = ws;  ws += NHD;
  bf16* kT    = ws;  ws += NHD;
  bf16* vT    = ws;  ws += NHD;
  bf16* g_bf  = ws;  ws += NHD;
  bf16* mid   = h_bf;  // reuse: h_bf dead after gemm_proj

  cast_kernel<<<4096, 256, 0, stream>>>(h, h_bf, (int)NHD);
  cast_kernel<<<512, 256, 0, stream>>>(Wq, Wcat, (int)NW);
  cast_kernel<<<512, 256, 0, stream>>>(Wk, Wcat + NW, (int)NW);
  cast_kernel<<<512, 256, 0, stream>>>(Wv, Wcat + 2 * NW, (int)NW);
  cast_kernel<<<512, 256, 0, stream>>>(Wg, Wcat + 3 * NW, (int)NW);
  cast_kernel<<<512, 256, 0, stream>>>(Wo, Wo_bf, (int)NW);

  gemm_proj<<<dim3(32, 128), 256, 0, stream>>>(h_bf, Wcat, bg, q_bf, kT, vT, g_bf);
  scan_kernel<<<256, 256, 0, stream>>>(q_bf, kT, vT, g_bf, mid);
  gemm_out<<<dim3(8, 128), 256, 0, stream>>>(mid, Wo_bf, out);
}

// Round 3
// 896.899 us; speedup vs baseline: 1.1518x; 1.1518x over previous
//
#include <hip/hip_runtime.h>
#include <math.h>

#define B_ 4
#define S_ 4096
#define D_ 1024
#define T_ 128
#define NC_ 32
#define DECAY_ 0.95f
#define NPAIR_ 528   // 32*33/2 chunk pairs per batch

typedef __bf16 bf16;
typedef __bf16 bf16x8 __attribute__((ext_vector_type(8)));
typedef __bf16 bf16x4 __attribute__((ext_vector_type(4)));
typedef float f32x4 __attribute__((ext_vector_type(4)));

__device__ __forceinline__ f32x4 mfma16(bf16x8 a, bf16x8 b, f32x4 c) {
  return __builtin_amdgcn_mfma_f32_16x16x32_bf16(a, b, c, 0, 0, 0);
}

// ---------------- fp32 -> bf16 cast ----------------
__global__ void cast_kernel(const float* __restrict__ src, bf16* __restrict__ dst, int n) {
  int i = (blockIdx.x * blockDim.x + threadIdx.x) * 4;
  int stride = gridDim.x * blockDim.x * 4;
  for (; i < n; i += stride) {
    float4 f = *(const float4*)(src + i);
    bf16x4 o = { (bf16)f.x, (bf16)f.y, (bf16)f.z, (bf16)f.w };
    *(bf16x4*)(dst + i) = o;
  }
}

// ---------------- fused projection GEMM ----------------
// A[16384][1024] bf16, W[4096][1024] bf16 (y = x @ W.T)
// n0 block: [0,1024): q natural, [1024,2048): k natural,
// [2048,3072): v -> vT[b][chunk][e][t], [3072,4096): gate = sigmoid(.+bg) natural
__global__ __launch_bounds__(256) void gemm_proj(
    const bf16* __restrict__ A, const bf16* __restrict__ W,
    const float* __restrict__ bg,
    bf16* __restrict__ qo, bf16* __restrict__ ko,
    bf16* __restrict__ vT, bf16* __restrict__ go)
{
  __shared__ bf16 As[128 * 32];
  __shared__ bf16 Bs[128 * 32];
  const int K = 1024;
  int m0 = blockIdx.y * 128;
  int n0 = blockIdx.x * 128;
  int tid = threadIdx.x;
  int l = tid & 63, w = tid >> 6;
  int wr = w >> 1, wc = w & 1;

  const bf16* Ab = A + (long)m0 * K;
  const bf16* Wb = W + (long)n0 * K;
  int lrow = tid >> 2, lcol = (tid & 3) * 8;

  f32x4 acc[4][4] = {};

  bf16x8 a0 = *(const bf16x8*)(Ab + (long)lrow * K + lcol);
  bf16x8 a1 = *(const bf16x8*)(Ab + (long)(lrow + 64) * K + lcol);
  bf16x8 b0 = *(const bf16x8*)(Wb + (long)lrow * K + lcol);
  bf16x8 b1 = *(const bf16x8*)(Wb + (long)(lrow + 64) * K + lcol);

  for (int k0 = 0; k0 < K; k0 += 32) {
    __syncthreads();
    *(bf16x8*)(As + tid * 8) = a0;
    *(bf16x8*)(As + (tid + 256) * 8) = a1;
    *(bf16x8*)(Bs + tid * 8) = b0;
    *(bf16x8*)(Bs + (tid + 256) * 8) = b1;
    __syncthreads();
    if (k0 + 32 < K) {
      a0 = *(const bf16x8*)(Ab + (long)lrow * K + k0 + 32 + lcol);
      a1 = *(const bf16x8*)(Ab + (long)(lrow + 64) * K + k0 + 32 + lcol);
      b0 = *(const bf16x8*)(Wb + (long)lrow * K + k0 + 32 + lcol);
      b1 = *(const bf16x8*)(Wb + (long)(lrow + 64) * K + k0 + 32 + lcol);
    }
    bf16x8 af[4], bfr[4];
#pragma unroll
    for (int m = 0; m < 4; ++m)
      af[m] = *(const bf16x8*)(As + (wr * 64 + m * 16 + (l & 15)) * 32 + (l >> 4) * 8);
#pragma unroll
    for (int n = 0; n < 4; ++n)
      bfr[n] = *(const bf16x8*)(Bs + (wc * 64 + n * 16 + (l & 15)) * 32 + (l >> 4) * 8);
#pragma unroll
    for (int m = 0; m < 4; ++m)
#pragma unroll
      for (int n = 0; n < 4; ++n)
        acc[m][n] = mfma16(af[m], bfr[n], acc[m][n]);
  }

  int widx = n0 >> 10;          // 0=q 1=k 2=v 3=g
  int b = m0 >> 12;
  int srow0 = m0 & 4095;
  int chunk = srow0 >> 7;

#pragma unroll
  for (int m = 0; m < 4; ++m) {
    int row = wr * 64 + m * 16 + (l >> 4) * 4;
#pragma unroll
    for (int n = 0; n < 4; ++n) {
      int col = (n0 & 1023) + wc * 64 + n * 16 + (l & 15);
      if (widx == 2) {
        bf16x4 pk = { (bf16)acc[m][n][0], (bf16)acc[m][n][1],
                      (bf16)acc[m][n][2], (bf16)acc[m][n][3] };
        *(bf16x4*)(vT + ((long)(b * NC_ + chunk) * D_ + col) * T_ + row) = pk;
      } else if (widx < 2) {
        bf16* dst = (widx == 0) ? qo : ko;
#pragma unroll
        for (int r = 0; r < 4; ++r)
          dst[(long)(m0 + row + r) * D_ + col] = (bf16)acc[m][n][r];
      } else {
        float bgv = bg[col];
#pragma unroll
        for (int r = 0; r < 4; ++r) {
          float x = acc[m][n][r] + bgv;
          go[(long)(m0 + row + r) * D_ + col] = (bf16)(1.0f / (1.0f + __expf(-x)));
        }
      }
    }
  }
}

// ---------------- QK^T pass ----------------
// block = (pair p, batch b). P_nj[128 t][128 t'] = c_nj * q_n k_j^T, bf16.
__global__ __launch_bounds__(256) void qk_kernel(
    const bf16* __restrict__ q, const bf16* __restrict__ k,
    bf16* __restrict__ Plo, bf16* __restrict__ Phi)
{
  __shared__ bf16 As[128 * 32];
  __shared__ bf16 Bs[128 * 32];
  const int K = 1024;
  int p = blockIdx.x, b = blockIdx.y;
  int n = (int)((sqrtf(8.f * (float)p + 1.f) - 1.f) * 0.5f);
  while ((n + 1) * (n + 2) / 2 <= p) ++n;
  while (n * (n + 1) / 2 > p) --n;
  int j = p - n * (n + 1) / 2;

  int tid = threadIdx.x;
  int l = tid & 63, w = tid >> 6;
  int wr = w >> 1, wc = w & 1;

  const bf16* Ab = q + (long)(b * S_ + n * T_) * K;
  const bf16* Wb = k + (long)(b * S_ + j * T_) * K;
  int lrow = tid >> 2, lcol = (tid & 3) * 8;

  f32x4 acc[4][4] = {};

  bf16x8 a0 = *(const bf16x8*)(Ab + (long)lrow * K + lcol);
  bf16x8 a1 = *(const bf16x8*)(Ab + (long)(lrow + 64) * K + lcol);
  bf16x8 b0 = *(const bf16x8*)(Wb + (long)lrow * K + lcol);
  bf16x8 b1 = *(const bf16x8*)(Wb + (long)(lrow + 64) * K + lcol);

  for (int k0 = 0; k0 < K; k0 += 32) {
    __syncthreads();
    *(bf16x8*)(As + tid * 8) = a0;
    *(bf16x8*)(As + (tid + 256) * 8) = a1;
    *(bf16x8*)(Bs + tid * 8) = b0;
    *(bf16x8*)(Bs + (tid + 256) * 8) = b1;
    __syncthreads();
    if (k0 + 32 < K) {
      a0 = *(const bf16x8*)(Ab + (long)lrow * K + k0 + 32 + lcol);
      a1 = *(const bf16x8*)(Ab + (long)(lrow + 64) * K + k0 + 32 + lcol);
      b0 = *(const bf16x8*)(Wb + (long)lrow * K + k0 + 32 + lcol);
      b1 = *(const bf16x8*)(Wb + (long)(lrow + 64) * K + k0 + 32 + lcol);
    }
    bf16x8 af[4], bfr[4];
#pragma unroll
    for (int m = 0; m < 4; ++m)
      af[m] = *(const bf16x8*)(As + (wr * 64 + m * 16 + (l & 15)) * 32 + (l >> 4) * 8);
#pragma unroll
    for (int nn = 0; nn < 4; ++nn)
      bfr[nn] = *(const bf16x8*)(Bs + (wc * 64 + nn * 16 + (l & 15)) * 32 + (l >> 4) * 8);
#pragma unroll
    for (int m = 0; m < 4; ++m)
#pragma unroll
      for (int nn = 0; nn < 4; ++nn)
        acc[m][nn] = mfma16(af[m], bfr[nn], acc[m][nn]);
  }

  float c = powf(DECAY_, (float)(n - j)) * ((1.0f - DECAY_) / (float)T_);
  int tile = b * NPAIR_ + p;
  bf16* Pt = (tile < 1024) ? (Plo + (long)tile * 16384)
                           : (Phi + (long)(tile - 1024) * 16384);

#pragma unroll
  for (int m = 0; m < 4; ++m) {
    int row = wr * 64 + m * 16 + (l >> 4) * 4;
#pragma unroll
    for (int nn = 0; nn < 4; ++nn) {
      int col = wc * 64 + nn * 16 + (l & 15);
#pragma unroll
      for (int r = 0; r < 4; ++r)
        Pt[(long)(row + r) * T_ + col] = (bf16)(acc[m][nn][r] * c);
    }
  }
}

// ---------------- PV pass (direct-from-L2, no LDS) ----------------
// block = (e-tile, n desc, b). out[128 t][128 e] = sum_j P_nj v_j ; gate fused.
__global__ __launch_bounds__(256) void pv_kernel(
    const bf16* __restrict__ Plo, const bf16* __restrict__ Phi,
    const bf16* __restrict__ vT, const bf16* __restrict__ g,
    bf16* __restrict__ mid)
{
  int et = blockIdx.x;
  int n  = 31 - blockIdx.y;     // long blocks dispatch first
  int b  = blockIdx.z;
  int e0 = et * 128;
  int tid = threadIdx.x, l = tid & 63, w = tid >> 6;
  int wr = w >> 1, wc = w & 1;

  f32x4 acc[4][4] = {};
  int arow = wr * 64 + (l & 15);
  int brow = e0 + wc * 64 + (l & 15);
  int koff = (l >> 4) * 8;
  int pbase = b * NPAIR_ + n * (n + 1) / 2;

  for (int j = 0; j <= n; ++j) {
    int tile = pbase + j;
    const bf16* Pt = (tile < 1024) ? (Plo + (long)tile * 16384)
                                   : (Phi + (long)(tile - 1024) * 16384);
    const bf16* Vt = vT + (long)(b * NC_ + j) * D_ * T_;
#pragma unroll
    for (int kk = 0; kk < 4; ++kk) {
      bf16x8 af[4], bv[4];
#pragma unroll
      for (int m = 0; m < 4; ++m)
        af[m] = *(const bf16x8*)(Pt + (long)(arow + m * 16) * T_ + kk * 32 + koff);
#pragma unroll
      for (int nn = 0; nn < 4; ++nn)
        bv[nn] = *(const bf16x8*)(Vt + (long)(brow + nn * 16) * T_ + kk * 32 + koff);
#pragma unroll
      for (int m = 0; m < 4; ++m)
#pragma unroll
        for (int nn = 0; nn < 4; ++nn)
          acc[m][nn] = mfma16(af[m], bv[nn], acc[m][nn]);
    }
  }

#pragma unroll
  for (int m = 0; m < 4; ++m) {
    int trow = n * T_ + wr * 64 + m * 16 + (l >> 4) * 4;
#pragma unroll
    for (int nn = 0; nn < 4; ++nn) {
      int col = e0 + wc * 64 + nn * 16 + (l & 15);
#pragma unroll
      for (int r = 0; r < 4; ++r) {
        long idx = ((long)b * S_ + trow + r) * D_ + col;
        float gv = (float)g[idx];
        mid[idx] = (bf16)(acc[m][nn][r] * gv);
      }
    }
  }
}

// ---------------- output GEMM (fp32 out) ----------------
__global__ __launch_bounds__(256) void gemm_out(
    const bf16* __restrict__ A, const bf16* __restrict__ W,
    float* __restrict__ C)
{
  __shared__ bf16 As[128 * 32];
  __shared__ bf16 Bs[128 * 32];
  const int K = 1024;
  int m0 = blockIdx.y * 128;
  int n0 = blockIdx.x * 128;
  int tid = threadIdx.x;
  int l = tid & 63, w = tid >> 6;
  int wr = w >> 1, wc = w & 1;

  const bf16* Ab = A + (long)m0 * K;
  const bf16* Wb = W + (long)n0 * K;
  int lrow = tid >> 2, lcol = (tid & 3) * 8;

  f32x4 acc[4][4] = {};

  bf16x8 a0 = *(const bf16x8*)(Ab + (long)lrow * K + lcol);
  bf16x8 a1 = *(const bf16x8*)(Ab + (long)(lrow + 64) * K + lcol);
  bf16x8 b0 = *(const bf16x8*)(Wb + (long)lrow * K + lcol);
  bf16x8 b1 = *(const bf16x8*)(Wb + (long)(lrow + 64) * K + lcol);

  for (int k0 = 0; k0 < K; k0 += 32) {
    __syncthreads();
    *(bf16x8*)(As + tid * 8) = a0;
    *(bf16x8*)(As + (tid + 256) * 8) = a1;
    *(bf16x8*)(Bs + tid * 8) = b0;
    *(bf16x8*)(Bs + (tid + 256) * 8) = b1;
    __syncthreads();
    if (k0 + 32 < K) {
      a0 = *(const bf16x8*)(Ab + (long)lrow * K + k0 + 32 + lcol);
      a1 = *(const bf16x8*)(Ab + (long)(lrow + 64) * K + k0 + 32 + lcol);
      b0 = *(const bf16x8*)(Wb + (long)lrow * K + k0 + 32 + lcol);
      b1 = *(const bf16x8*)(Wb + (long)(lrow + 64) * K + k0 + 32 + lcol);
    }
    bf16x8 af[4], bfr[4];
#pragma unroll
    for (int m = 0; m < 4; ++m)
      af[m] = *(const bf16x8*)(As + (wr * 64 + m * 16 + (l & 15)) * 32 + (l >> 4) * 8);
#pragma unroll
    for (int n = 0; n < 4; ++n)
      bfr[n] = *(const bf16x8*)(Bs + (wc * 64 + n * 16 + (l & 15)) * 32 + (l >> 4) * 8);
#pragma unroll
    for (int m = 0; m < 4; ++m)
#pragma unroll
      for (int n = 0; n < 4; ++n)
        acc[m][n] = mfma16(af[m], bfr[n], acc[m][n]);
  }

#pragma unroll
  for (int m = 0; m < 4; ++m) {
    int row = m0 + wr * 64 + m * 16 + (l >> 4) * 4;
#pragma unroll
    for (int n = 0; n < 4; ++n) {
      int col = n0 + wc * 64 + n * 16 + (l & 15);
#pragma unroll
      for (int r = 0; r < 4; ++r)
        C[(long)(row + r) * D_ + col] = acc[m][n][r];
    }
  }
}

// ---------------- launcher ----------------
extern "C" void kernel_launch(void* const* d_in, const int* in_sizes, int n_in,
                              void* d_out, int out_size, void* d_ws, size_t ws_size,
                              hipStream_t stream) {
  const float* h  = (const float*)d_in[0];
  const float* Wq = (const float*)d_in[2];
  const float* Wk = (const float*)d_in[3];
  const float* Wv = (const float*)d_in[4];
  const float* Wo = (const float*)d_in[5];
  const float* Wg = (const float*)d_in[6];
  const float* bg = (const float*)d_in[7];
  float* out = (float*)d_out;

  bf16* ws = (bf16*)d_ws;
  const long NHD = (long)B_ * S_ * D_;   // 16,777,216 (= exactly 1024 P tiles)
  const long NW  = (long)D_ * D_;

  bf16* h_bf  = ws;  ws += NHD;          // dead after proj -> reused as P_lo
  bf16* Wcat  = ws;  ws += 4 * NW;
  bf16* Wo_bf = ws;  ws += NW;
  bf16* q_bf  = ws;  ws += NHD;          // dead after qk -> reused as mid
  bf16* k_bf  = ws;  ws += NHD;
  bf16* vT    = ws;  ws += NHD;
  bf16* g_bf  = ws;  ws += NHD;
  bf16* P_hi  = ws;  ws += (long)(4 * NPAIR_ - 1024) * 16384;  // 1088 tiles

  bf16* P_lo = h_bf;
  bf16* mid  = q_bf;

  cast_kernel<<<4096, 256, 0, stream>>>(h, h_bf, (int)NHD);
  cast_kernel<<<512, 256, 0, stream>>>(Wq, Wcat, (int)NW);
  cast_kernel<<<512, 256, 0, stream>>>(Wk, Wcat + NW, (int)NW);
  cast_kernel<<<512, 256, 0, stream>>>(Wv, Wcat + 2 * NW, (int)NW);
  cast_kernel<<<512, 256, 0, stream>>>(Wg, Wcat + 3 * NW, (int)NW);
  cast_kernel<<<512, 256, 0, stream>>>(Wo, Wo_bf, (int)NW);

  gemm_proj<<<dim3(32, 128), 256, 0, stream>>>(h_bf, Wcat, bg, q_bf, k_bf, vT, g_bf);
  qk_kernel<<<dim3(NPAIR_, 4), 256, 0, stream>>>(q_bf, k_bf, P_lo, P_hi);
  pv_kernel<<<dim3(8, 32, 4), 256, 0, stream>>>(P_lo, P_hi, vT, g_bf, mid);
  gemm_out<<<dim3(8, 128), 256, 0, stream>>>(mid, Wo_bf, out);
}

// Round 5
// 627.688 us; speedup vs baseline: 1.6458x; 1.4289x over previous
//
#include <hip/hip_runtime.h>
#include <math.h>

#define B_ 4
#define S_ 4096
#define D_ 1024
#define T_ 128
#define NC_ 32
#define DECAY_ 0.95f
#define NPAIR_ 528   // 32*33/2 chunk pairs per batch

typedef __bf16 bf16;
typedef __bf16 bf16x8 __attribute__((ext_vector_type(8)));
typedef __bf16 bf16x4 __attribute__((ext_vector_type(4)));
typedef float f32x4 __attribute__((ext_vector_type(4)));

__device__ __forceinline__ f32x4 mfma16(bf16x8 a, bf16x8 b, f32x4 c) {
  return __builtin_amdgcn_mfma_f32_16x16x32_bf16(a, b, c, 0, 0, 0);
}

// async global -> LDS, 16B per lane. lds base must be wave-uniform; HW writes
// base + lane*16. Our LDS layout is linear in tid so this matches As+tid*8.
__device__ __forceinline__ void gload16(const bf16* g, bf16* l) {
  __builtin_amdgcn_global_load_lds(
      (const __attribute__((address_space(1))) unsigned int*)g,
      (__attribute__((address_space(3))) unsigned int*)l, 16, 0, 0);
}

// ---------------- fp32 -> bf16 casts ----------------
__global__ void cast_kernel(const float* __restrict__ src, bf16* __restrict__ dst, int n) {
  int i = (blockIdx.x * blockDim.x + threadIdx.x) * 4;
  int stride = gridDim.x * blockDim.x * 4;
  for (; i < n; i += stride) {
    float4 f = *(const float4*)(src + i);
    bf16x4 o = { (bf16)f.x, (bf16)f.y, (bf16)f.z, (bf16)f.w };
    *(bf16x4*)(dst + i) = o;
  }
}

// all 5 weight matrices in one launch: Wq|Wk|Wv|Wg -> Wcat, Wo -> Wo_bf
__global__ void wcast_kernel(const float* __restrict__ Wq, const float* __restrict__ Wk,
                             const float* __restrict__ Wv, const float* __restrict__ Wg,
                             const float* __restrict__ Wo,
                             bf16* __restrict__ Wcat, bf16* __restrict__ Wo_bf) {
  const int NW = 1 << 20;
  long gid = ((long)blockIdx.x * blockDim.x + threadIdx.x) * 4;  // [0, 5*NW)
  int sel = (int)(gid >> 20);
  int off = (int)(gid & (NW - 1));
  const float* src = (sel == 0) ? Wq : (sel == 1) ? Wk : (sel == 2) ? Wv
                   : (sel == 3) ? Wg : Wo;
  bf16* dst = (sel < 4) ? (Wcat + (long)sel * NW) : Wo_bf;
  float4 f = *(const float4*)(src + off);
  bf16x4 o = { (bf16)f.x, (bf16)f.y, (bf16)f.z, (bf16)f.w };
  *(bf16x4*)(dst + off) = o;
}

// ---------------- fused projection GEMM ----------------
// A[16384][1024] bf16, W[4096][1024] bf16 (y = x @ W.T)
// n0: [0,1K): q natural, [1K,2K): k natural, [2K,3K): v -> vT[b][c][e][t],
// [3K,4K): gate = sigmoid(.+bg) natural
__global__ __launch_bounds__(256) void gemm_proj(
    const bf16* __restrict__ A, const bf16* __restrict__ W,
    const float* __restrict__ bg,
    bf16* __restrict__ qo, bf16* __restrict__ ko,
    bf16* __restrict__ vT, bf16* __restrict__ go)
{
  __shared__ __align__(16) bf16 As[128 * 32];
  __shared__ __align__(16) bf16 Bs[128 * 32];
  const int K = 1024;
  int m0 = blockIdx.y * 128;
  int n0 = blockIdx.x * 128;
  int tid = threadIdx.x;
  int l = tid & 63, w = tid >> 6;
  int wr = w >> 1, wc = w & 1;
  int wbase = (tid >> 6) << 9;   // wave LDS base, elems

  const bf16* Ab = A + (long)m0 * K;
  const bf16* Wb = W + (long)n0 * K;
  int lrow = tid >> 2, lcol = (tid & 3) * 8;

  f32x4 acc[4][4] = {};

  for (int k0 = 0; k0 < K; k0 += 32) {
    gload16(Ab + (long)lrow * K + k0 + lcol, As + wbase);
    gload16(Ab + (long)(lrow + 64) * K + k0 + lcol, As + 2048 + wbase);
    gload16(Wb + (long)lrow * K + k0 + lcol, Bs + wbase);
    gload16(Wb + (long)(lrow + 64) * K + k0 + lcol, Bs + 2048 + wbase);
    __syncthreads();
    bf16x8 af[4], bfr[4];
#pragma unroll
    for (int m = 0; m < 4; ++m)
      af[m] = *(const bf16x8*)(As + (wr * 64 + m * 16 + (l & 15)) * 32 + (l >> 4) * 8);
#pragma unroll
    for (int n = 0; n < 4; ++n)
      bfr[n] = *(const bf16x8*)(Bs + (wc * 64 + n * 16 + (l & 15)) * 32 + (l >> 4) * 8);
#pragma unroll
    for (int m = 0; m < 4; ++m)
#pragma unroll
      for (int n = 0; n < 4; ++n)
        acc[m][n] = mfma16(af[m], bfr[n], acc[m][n]);
    __syncthreads();
  }

  int widx = n0 >> 10;          // 0=q 1=k 2=v 3=g
  int b = m0 >> 12;
  int chunk = (m0 & 4095) >> 7;

#pragma unroll
  for (int m = 0; m < 4; ++m) {
    int row = wr * 64 + m * 16 + (l >> 4) * 4;
#pragma unroll
    for (int n = 0; n < 4; ++n) {
      int col = (n0 & 1023) + wc * 64 + n * 16 + (l & 15);
      if (widx == 2) {
        bf16x4 pk = { (bf16)acc[m][n][0], (bf16)acc[m][n][1],
                      (bf16)acc[m][n][2], (bf16)acc[m][n][3] };
        *(bf16x4*)(vT + ((long)(b * NC_ + chunk) * D_ + col) * T_ + row) = pk;
      } else if (widx < 2) {
        bf16* dst = (widx == 0) ? qo : ko;
#pragma unroll
        for (int r = 0; r < 4; ++r)
          dst[(long)(m0 + row + r) * D_ + col] = (bf16)acc[m][n][r];
      } else {
        float bgv = bg[col];
#pragma unroll
        for (int r = 0; r < 4; ++r) {
          float x = acc[m][n][r] + bgv;
          go[(long)(m0 + row + r) * D_ + col] = (bf16)(1.0f / (1.0f + __expf(-x)));
        }
      }
    }
  }
}

// ---------------- QK^T pass ----------------
// block = (pair p, batch b). P_nj[128 t][128 t'] = c_nj * q_n k_j^T, bf16.
__global__ __launch_bounds__(256) void qk_kernel(
    const bf16* __restrict__ q, const bf16* __restrict__ k,
    bf16* __restrict__ Plo, bf16* __restrict__ Phi)
{
  __shared__ __align__(16) bf16 As[128 * 32];
  __shared__ __align__(16) bf16 Bs[128 * 32];
  const int K = 1024;
  int p = blockIdx.x, b = blockIdx.y;
  int n = (int)((sqrtf(8.f * (float)p + 1.f) - 1.f) * 0.5f);
  while ((n + 1) * (n + 2) / 2 <= p) ++n;
  while (n * (n + 1) / 2 > p) --n;
  int j = p - n * (n + 1) / 2;

  int tid = threadIdx.x;
  int l = tid & 63, w = tid >> 6;
  int wr = w >> 1, wc = w & 1;
  int wbase = (tid >> 6) << 9;

  const bf16* Ab = q + (long)(b * S_ + n * T_) * K;
  const bf16* Wb = k + (long)(b * S_ + j * T_) * K;
  int lrow = tid >> 2, lcol = (tid & 3) * 8;

  f32x4 acc[4][4] = {};

  for (int k0 = 0; k0 < K; k0 += 32) {
    gload16(Ab + (long)lrow * K + k0 + lcol, As + wbase);
    gload16(Ab + (long)(lrow + 64) * K + k0 + lcol, As + 2048 + wbase);
    gload16(Wb + (long)lrow * K + k0 + lcol, Bs + wbase);
    gload16(Wb + (long)(lrow + 64) * K + k0 + lcol, Bs + 2048 + wbase);
    __syncthreads();
    bf16x8 af[4], bfr[4];
#pragma unroll
    for (int m = 0; m < 4; ++m)
      af[m] = *(const bf16x8*)(As + (wr * 64 + m * 16 + (l & 15)) * 32 + (l >> 4) * 8);
#pragma unroll
    for (int nn = 0; nn < 4; ++nn)
      bfr[nn] = *(const bf16x8*)(Bs + (wc * 64 + nn * 16 + (l & 15)) * 32 + (l >> 4) * 8);
#pragma unroll
    for (int m = 0; m < 4; ++m)
#pragma unroll
      for (int nn = 0; nn < 4; ++nn)
        acc[m][nn] = mfma16(af[m], bfr[nn], acc[m][nn]);
    __syncthreads();
  }

  float c = powf(DECAY_, (float)(n - j)) * ((1.0f - DECAY_) / (float)T_);
  int tile = b * NPAIR_ + p;
  bf16* Pt = (tile < 1024) ? (Plo + (long)tile * 16384)
                           : (Phi + (long)(tile - 1024) * 16384);

#pragma unroll
  for (int m = 0; m < 4; ++m) {
    int row = wr * 64 + m * 16 + (l >> 4) * 4;
#pragma unroll
    for (int nn = 0; nn < 4; ++nn) {
      int col = wc * 64 + nn * 16 + (l & 15);
#pragma unroll
      for (int r = 0; r < 4; ++r)
        Pt[(long)(row + r) * T_ + col] = (bf16)(acc[m][nn][r] * c);
    }
  }
}

// ---------------- PV pass (LDS-staged GEMM over K=(n+1)*128) ----------------
// block = (e-tile, n desc, b). out[128 t][128 e] = sum_j P_nj v_j ; gate fused.
__global__ __launch_bounds__(256) void pv_kernel(
    const bf16* __restrict__ Plo, const bf16* __restrict__ Phi,
    const bf16* __restrict__ vT, const bf16* __restrict__ g,
    bf16* __restrict__ mid)
{
  __shared__ __align__(16) bf16 As[128 * 32];
  __shared__ __align__(16) bf16 Bs[128 * 32];
  int et = blockIdx.x;
  int n  = 31 - blockIdx.y;     // long blocks dispatch first
  int b  = blockIdx.z;
  int e0 = et * 128;
  int tid = threadIdx.x, l = tid & 63, w = tid >> 6;
  int wr = w >> 1, wc = w & 1;
  int wbase = (tid >> 6) << 9;
  int lrow = tid >> 2, lcol = (tid & 3) * 8;
  int pbase = b * NPAIR_ + n * (n + 1) / 2;

  f32x4 acc[4][4] = {};

  for (int j = 0; j <= n; ++j) {
    int tile = pbase + j;
    const bf16* Pt = (tile < 1024) ? (Plo + (long)tile * 16384)
                                   : (Phi + (long)(tile - 1024) * 16384);
    const bf16* Vt = vT + (long)(b * NC_ + j) * D_ * T_ + (long)e0 * T_;
#pragma unroll
    for (int kk = 0; kk < 4; ++kk) {
      int k0 = kk * 32;
      gload16(Pt + (long)lrow * T_ + k0 + lcol, As + wbase);
      gload16(Pt + (long)(lrow + 64) * T_ + k0 + lcol, As + 2048 + wbase);
      gload16(Vt + (long)lrow * T_ + k0 + lcol, Bs + wbase);
      gload16(Vt + (long)(lrow + 64) * T_ + k0 + lcol, Bs + 2048 + wbase);
      __syncthreads();
      bf16x8 af[4], bv[4];
#pragma unroll
      for (int m = 0; m < 4; ++m)
        af[m] = *(const bf16x8*)(As + (wr * 64 + m * 16 + (l & 15)) * 32 + (l >> 4) * 8);
#pragma unroll
      for (int nn = 0; nn < 4; ++nn)
        bv[nn] = *(const bf16x8*)(Bs + (wc * 64 + nn * 16 + (l & 15)) * 32 + (l >> 4) * 8);
#pragma unroll
      for (int m = 0; m < 4; ++m)
#pragma unroll
        for (int nn = 0; nn < 4; ++nn)
          acc[m][nn] = mfma16(af[m], bv[nn], acc[m][nn]);
      __syncthreads();
    }
  }

#pragma unroll
  for (int m = 0; m < 4; ++m) {
    int trow = n * T_ + wr * 64 + m * 16 + (l >> 4) * 4;
#pragma unroll
    for (int nn = 0; nn < 4; ++nn) {
      int col = e0 + wc * 64 + nn * 16 + (l & 15);
#pragma unroll
      for (int r = 0; r < 4; ++r) {
        long idx = ((long)b * S_ + trow + r) * D_ + col;
        float gv = (float)g[idx];
        mid[idx] = (bf16)(acc[m][nn][r] * gv);
      }
    }
  }
}

// ---------------- output GEMM (fp32 out) ----------------
__global__ __launch_bounds__(256) void gemm_out(
    const bf16* __restrict__ A, const bf16* __restrict__ W,
    float* __restrict__ C)
{
  __shared__ __align__(16) bf16 As[128 * 32];
  __shared__ __align__(16) bf16 Bs[128 * 32];
  const int K = 1024;
  int m0 = blockIdx.y * 128;
  int n0 = blockIdx.x * 128;
  int tid = threadIdx.x;
  int l = tid & 63, w = tid >> 6;
  int wr = w >> 1, wc = w & 1;
  int wbase = (tid >> 6) << 9;

  const bf16* Ab = A + (long)m0 * K;
  const bf16* Wb = W + (long)n0 * K;
  int lrow = tid >> 2, lcol = (tid & 3) * 8;

  f32x4 acc[4][4] = {};

  for (int k0 = 0; k0 < K; k0 += 32) {
    gload16(Ab + (long)lrow * K + k0 + lcol, As + wbase);
    gload16(Ab + (long)(lrow + 64) * K + k0 + lcol, As + 2048 + wbase);
    gload16(Wb + (long)lrow * K + k0 + lcol, Bs + wbase);
    gload16(Wb + (long)(lrow + 64) * K + k0 + lcol, Bs + 2048 + wbase);
    __syncthreads();
    bf16x8 af[4], bfr[4];
#pragma unroll
    for (int m = 0; m < 4; ++m)
      af[m] = *(const bf16x8*)(As + (wr * 64 + m * 16 + (l & 15)) * 32 + (l >> 4) * 8);
#pragma unroll
    for (int n = 0; n < 4; ++n)
      bfr[n] = *(const bf16x8*)(Bs + (wc * 64 + n * 16 + (l & 15)) * 32 + (l >> 4) * 8);
#pragma unroll
    for (int m = 0; m < 4; ++m)
#pragma unroll
      for (int n = 0; n < 4; ++n)
        acc[m][n] = mfma16(af[m], bfr[n], acc[m][n]);
    __syncthreads();
  }

#pragma unroll
  for (int m = 0; m < 4; ++m) {
    int row = m0 + wr * 64 + m * 16 + (l >> 4) * 4;
#pragma unroll
    for (int n = 0; n < 4; ++n) {
      int col = n0 + wc * 64 + n * 16 + (l & 15);
#pragma unroll
      for (int r = 0; r < 4; ++r)
        C[(long)(row + r) * D_ + col] = acc[m][n][r];
    }
  }
}

// ---------------- launcher ----------------
extern "C" void kernel_launch(void* const* d_in, const int* in_sizes, int n_in,
                              void* d_out, int out_size, void* d_ws, size_t ws_size,
                              hipStream_t stream) {
  const float* h  = (const float*)d_in[0];
  const float* Wq = (const float*)d_in[2];
  const float* Wk = (const float*)d_in[3];
  const float* Wv = (const float*)d_in[4];
  const float* Wo = (const float*)d_in[5];
  const float* Wg = (const float*)d_in[6];
  const float* bg = (const float*)d_in[7];
  float* out = (float*)d_out;

  bf16* ws = (bf16*)d_ws;
  const long NHD = (long)B_ * S_ * D_;   // 16,777,216 (= exactly 1024 P tiles)
  const long NW  = (long)D_ * D_;

  bf16* h_bf  = ws;  ws += NHD;          // dead after proj -> reused as P_lo
  bf16* Wcat  = ws;  ws += 4 * NW;
  bf16* Wo_bf = ws;  ws += NW;
  bf16* q_bf  = ws;  ws += NHD;          // dead after qk -> reused as mid
  bf16* k_bf  = ws;  ws += NHD;
  bf16* vT    = ws;  ws += NHD;
  bf16* g_bf  = ws;  ws += NHD;
  bf16* P_hi  = ws;  ws += (long)(4 * NPAIR_ - 1024) * 16384;  // 1088 tiles

  bf16* P_lo = h_bf;
  bf16* mid  = q_bf;

  cast_kernel<<<4096, 256, 0, stream>>>(h, h_bf, (int)NHD);
  wcast_kernel<<<5120, 256, 0, stream>>>(Wq, Wk, Wv, Wg, Wo, Wcat, Wo_bf);

  gemm_proj<<<dim3(32, 128), 256, 0, stream>>>(h_bf, Wcat, bg, q_bf, k_bf, vT, g_bf);
  qk_kernel<<<dim3(NPAIR_, 4), 256, 0, stream>>>(q_bf, k_bf, P_lo, P_hi);
  pv_kernel<<<dim3(8, 32, 4), 256, 0, stream>>>(P_lo, P_hi, vT, g_bf, mid);
  gemm_out<<<dim3(8, 128), 256, 0, stream>>>(mid, Wo_bf, out);
}